// Round 2
// baseline (352.173 us; speedup 1.0000x reference)
//
#include <hip/hip_runtime.h>

#define DIM   4096
#define NKV   8
#define HD    128
#define KVDIM 1024   // NKV*HD
#define NB    8      // batch
#define TOTAL 16384

// x[b*KVDIM + j] = dot(emb[b,:], W_up[j,:])  -- one wave per (j,b) output
__global__ __launch_bounds__(256)
void k_up(const float* __restrict__ emb, const float* __restrict__ wup,
          float* __restrict__ x) {
    int wid  = blockIdx.x * 4 + (threadIdx.x >> 6);
    int lane = threadIdx.x & 63;
    int j = wid >> 3;      // 0..1023 (b inner: consecutive waves share the W_up row)
    int b = wid & 7;
    const float4* e = (const float4*)(emb + b * DIM);
    const float4* w = (const float4*)(wup + (long)j * DIM);
    float acc = 0.f;
    #pragma unroll
    for (int it = lane; it < DIM / 4; it += 64) {
        float4 ev = e[it], wv = w[it];
        acc += ev.x * wv.x + ev.y * wv.y + ev.z * wv.z + ev.w * wv.w;
    }
    #pragma unroll
    for (int off = 32; off; off >>= 1) acc += __shfl_down(acc, off, 64);
    if (lane == 0) x[b * KVDIM + j] = acc;
}

// y[b*DIM + o] = dot(val[b,:], W_down[o,:]),
// val[b,k] = x[b, (k>>9)*128 + (k&127)]  (repeat-interleave kv heads 4x)
// One wave per o, all 8 b's accumulated -> W_down row fetched exactly once.
__global__ __launch_bounds__(256)
void k_down(const float* __restrict__ x, const float* __restrict__ wdn,
            float* __restrict__ y) {
    int o    = blockIdx.x * 4 + (threadIdx.x >> 6);   // 0..4095
    int lane = threadIdx.x & 63;
    const float4* w = (const float4*)(wdn + (long)o * DIM);
    float acc[NB];
    #pragma unroll
    for (int b = 0; b < NB; b++) acc[b] = 0.f;
    for (int it = lane; it < DIM / 4; it += 64) {
        int k0 = it * 4;
        int kv = ((k0 >> 9) << 7) + (k0 & 127);   // aligned: 4 consecutive k stay in-block
        float4 wv = w[it];
        #pragma unroll
        for (int b = 0; b < NB; b++) {
            const float4 xv = *(const float4*)(x + b * KVDIM + kv);
            acc[b] += xv.x * wv.x + xv.y * wv.y + xv.z * wv.z + xv.w * wv.w;
        }
    }
    #pragma unroll
    for (int b = 0; b < NB; b++) {
        #pragma unroll
        for (int off = 32; off; off >>= 1) acc[b] += __shfl_down(acc[b], off, 64);
    }
    if (lane < NB) y[lane * DIM + o] = acc[lane];   // lane b holds acc[b] after bcast? no:
}

// NOTE: shuffle-reduce leaves the total in lane 0 only, so gather the 8 sums
// via lane 0. Simpler correct variant below overrides the line above.
__global__ __launch_bounds__(256)
void k_down_fix(const float* __restrict__ x, const float* __restrict__ wdn,
                float* __restrict__ y) {
    int o    = blockIdx.x * 4 + (threadIdx.x >> 6);
    int lane = threadIdx.x & 63;
    const float4* w = (const float4*)(wdn + (long)o * DIM);
    float acc[NB];
    #pragma unroll
    for (int b = 0; b < NB; b++) acc[b] = 0.f;
    for (int it = lane; it < DIM / 4; it += 64) {
        int k0 = it * 4;
        int kv = ((k0 >> 9) << 7) + (k0 & 127);
        float4 wv = w[it];
        #pragma unroll
        for (int b = 0; b < NB; b++) {
            const float4 xv = *(const float4*)(x + b * KVDIM + kv);
            acc[b] += xv.x * wv.x + xv.y * wv.y + xv.z * wv.z + xv.w * wv.w;
        }
    }
    #pragma unroll
    for (int b = 0; b < NB; b++) {
        #pragma unroll
        for (int off = 32; off; off >>= 1) acc[b] += __shfl_down(acc[b], off, 64);
        if (lane == 0) y[b * DIM + o] = acc[b];
    }
}

// out[row,:] = y[seq_id(row),:]   (16 KB fp32 row copy per block)
__global__ __launch_bounds__(256)
void k_bcast(const float* __restrict__ y, const int* __restrict__ seqlen,
             float4* __restrict__ out) {
    int row = blockIdx.x;
    int s = 0, acc = 0;
    #pragma unroll
    for (int i = 0; i < 7; i++) { acc += seqlen[i]; if (row >= acc) s = i + 1; }
    const float4* yr = (const float4*)(y + s * DIM);
    float4* orow = out + (long)row * (DIM / 4);
    #pragma unroll
    for (int c = threadIdx.x; c < DIM / 4; c += 256)
        orow[c] = yr[c];
}

extern "C" void kernel_launch(void* const* d_in, const int* in_sizes, int n_in,
                              void* d_out, int out_size, void* d_ws, size_t ws_size,
                              hipStream_t stream) {
    const float* emb = (const float*)d_in[0];
    const float* wup = (const float*)d_in[1];
    const float* wdn = (const float*)d_in[2];
    const int* seqlen = (const int*)d_in[3];

    float* x = (float*)d_ws;                               // 8*1024 fp32 = 32 KB
    float* y = x + NB * KVDIM;                             // 8*4096 fp32 = 128 KB

    k_up       <<<NB * KVDIM / 4, 256, 0, stream>>>(emb, wup, x);
    k_down_fix <<<DIM / 4,        256, 0, stream>>>(x, wdn, y);
    k_bcast    <<<TOTAL,          256, 0, stream>>>(y, seqlen, (float4*)d_out);
}